// Round 10
// baseline (282.806 us; speedup 1.0000x reference)
//
#include <hip/hip_runtime.h>
#include <math.h>

// Problem constants
constexpr int kB = 2;
constexpr int kC = 128;
constexpr int kN = 784;
constexpr float kInvT = 1.0f / 11.313708498984761f;  // 1/sqrt(C)
constexpr float kInvC = 1.0f / 128.0f;

constexpr size_t kOutElems  = (size_t)kB * kC * kN;  // 200704
constexpr size_t kAttnElems = (size_t)kB * kN * kN;  // 1229312

// Persistent grid: 768 blocks = 3/CU. Co-residency guaranteed by
// __launch_bounds__(256,3) (VGPR cap for 3 waves/EU = 3 blocks/CU of 256thr)
// and LDS 34.8 KB (160/34.8 -> 4 blocks/CU capacity).
constexpr int GRID = 768;

// dist tiling (phase 1): 676 tiles
constexpr int TK = 64, TQ = 64;
constexpr int NKT = 13, NQT = 13;
constexpr int CSP = 2, CH = 64;
constexpr int DSTR = 68;
constexpr int NDIST = kB * CSP * NKT * NQT;  // 676

// bmm tiling (phase 3): 728 tiles
constexpr int BKT = 64, NKT2 = 13;
constexpr int QSP = 14, QPB = 56, QCH = 28;
constexpr int BSTR = 68;
constexpr int NBMM = kB * 2 * NKT2 * QSP;  // 728

constexpr int NROWS = kB * kN;  // 1568 softmax rows

__device__ inline float wave_max(float v) {
#pragma unroll
    for (int o = 32; o > 0; o >>= 1) v = fmaxf(v, __shfl_xor(v, o, 64));
    return v;
}
__device__ inline float wave_sum(float v) {
#pragma unroll
    for (int o = 32; o > 0; o >>= 1) v += __shfl_xor(v, o, 64);
    return v;
}

// Software grid barrier: monotonic counter, agent(device)-scope acq-rel.
// Release on arrive publishes this block's prior global stores (incl. L2
// writeback across XCDs); acquire on the spin load invalidates stale L1/L2
// before the next phase reads. Bounded spin: a co-residency failure degrades
// to a wrong answer (visible bench fail), not a hang.
__device__ inline void gbarrier(unsigned* ctr, unsigned target) {
    __syncthreads();
    if (threadIdx.x == 0) {
        __hip_atomic_fetch_add(ctr, 1u, __ATOMIC_ACQ_REL, __HIP_MEMORY_SCOPE_AGENT);
        long spin = 0;
        while (__hip_atomic_load(ctr, __ATOMIC_ACQUIRE, __HIP_MEMORY_SCOPE_AGENT) < target) {
            __builtin_amdgcn_s_sleep(8);
            if (++spin > (1L << 20)) break;  // ~0.2 s safety valve
        }
    }
    __syncthreads();
}

__global__ __launch_bounds__(256, 3) void mega_kernel(const float* __restrict__ qg,
                                                      const float* __restrict__ kg,
                                                      const float* __restrict__ vg,
                                                      float* __restrict__ out,
                                                      float* __restrict__ attn,
                                                      float* __restrict__ P,
                                                      float* __restrict__ D1,
                                                      unsigned* __restrict__ bar) {
    const int t = threadIdx.x;

    __shared__ union {
        struct { float ks[CH][DSTR]; float qs[CH][DSTR]; } d;   // 34.8 KB
        struct { float vT[QCH][BSTR]; float aT[QCH][BSTR]; } m; // 15.2 KB
    } sh;
    __shared__ float xred[4];

    // ================= Phase 1: dist tiles (64k x 64q, c-halves) =================
    for (int tile = blockIdx.x; tile < NDIST; tile += GRID) {
        int bid = tile;
        const int qt = bid % NQT; bid /= NQT;
        const int kt = bid % NKT; bid /= NKT;
        const int ch = bid & 1;   bid >>= 1;
        const int b  = bid;
        const int k0 = kt * TK;
        const int q0 = qt * TQ;

        const float* kb = kg + ((size_t)b * kC + ch * CH) * kN;
        const float* qb = qg + ((size_t)b * kC + ch * CH) * kN;

#pragma unroll
        for (int i = t; i < CH * 16; i += 256) {
            const int c  = i >> 4;
            const int x4 = (i & 15) << 2;
            *reinterpret_cast<float4*>(&sh.d.ks[c][x4]) =
                *reinterpret_cast<const float4*>(kb + (size_t)c * kN + min(k0 + x4, kN - 4));
            float4 qv = *reinterpret_cast<const float4*>(qb + (size_t)c * kN + min(q0 + x4, kN - 4));
            qv.x *= kInvT; qv.y *= kInvT; qv.z *= kInvT; qv.w *= kInvT;
            *reinterpret_cast<float4*>(&sh.d.qs[c][x4]) = qv;
        }
        __syncthreads();

        const int qx = (t & 15) << 2;
        const int kx = (t >> 4) << 2;

        float acc[4][4];
#pragma unroll
        for (int i = 0; i < 4; ++i)
#pragma unroll
            for (int j = 0; j < 4; ++j) acc[i][j] = 0.0f;

#pragma unroll 4
        for (int c = 0; c < CH; ++c) {
            const float4 kv = *reinterpret_cast<const float4*>(&sh.d.ks[c][kx]);
            const float4 qv = *reinterpret_cast<const float4*>(&sh.d.qs[c][qx]);
            const float kf[4] = {kv.x, kv.y, kv.z, kv.w};
            const float qf[4] = {qv.x, qv.y, qv.z, qv.w};
#pragma unroll
            for (int i = 0; i < 4; ++i)
#pragma unroll
                for (int j = 0; j < 4; ++j)
                    acc[i][j] += fabsf(qf[j] - kf[i]);
        }

        const int qcol = q0 + qx;
        if (qcol < kN) {
            float* dst = ch ? D1 : attn;
#pragma unroll
            for (int i = 0; i < 4; ++i) {
                const int krow = k0 + kx + i;
                if (krow < kN) {
                    *reinterpret_cast<float4*>(&dst[((size_t)b * kN + krow) * kN + qcol]) =
                        make_float4(acc[i][0], acc[i][1], acc[i][2], acc[i][3]);
                }
            }
        }
        __syncthreads();  // protect LDS before next tile
    }

    gbarrier(bar, GRID);

    // ================= Phase 2: softmax (block-per-row, proven body) =================
    {
        const int lane = t & 63, wid = t >> 6;
        const bool act = t < (kN / 4);  // 196
        for (int r = blockIdx.x; r < NROWS; r += GRID) {
            const size_t row = (size_t)r * kN;
            float4* A4 = reinterpret_cast<float4*>(attn + row);
            const float4* W4 = reinterpret_cast<const float4*>(D1 + row);

            __syncthreads();  // xred safe for reuse across iterations

            float4 x = make_float4(-1e30f, -1e30f, -1e30f, -1e30f);
            if (act) {
                x = A4[t];
                const float4 w = W4[t];
                x.x += w.x; x.y += w.y; x.z += w.z; x.w += w.w;
            }

            float m = fmaxf(fmaxf(x.x, x.y), fmaxf(x.z, x.w));
            m = wave_max(m);
            if (lane == 0) xred[wid] = m;
            __syncthreads();
            m = fmaxf(fmaxf(xred[0], xred[1]), fmaxf(xred[2], xred[3]));
            __syncthreads();

            float4 p;
            p.x = __expf((x.x - m) * kInvC);
            p.y = __expf((x.y - m) * kInvC);
            p.z = __expf((x.z - m) * kInvC);
            p.w = __expf((x.w - m) * kInvC);
            float lsum = p.x + p.y + p.z + p.w;  // inactive lanes: exp(-huge)=0
            lsum = wave_sum(lsum);
            if (lane == 0) xred[wid] = lsum;
            __syncthreads();
            const float inv = 1.0f / (xred[0] + xred[1] + xred[2] + xred[3]);
            if (act) {
                p.x *= inv; p.y *= inv; p.z *= inv; p.w *= inv;
                A4[t] = p;
            }
        }
    }

    gbarrier(bar, 2u * GRID);

    // ================= Phase 3: bmm partials (64c x 64k, qsplit 14) =================
    for (int tile = blockIdx.x; tile < NBMM; tile += GRID) {
        int bid = tile;
        const int qs = bid % QSP;   bid /= QSP;
        const int kt = bid % NKT2;  bid /= NKT2;
        const int ct = bid & 1;     bid >>= 1;
        const int b  = bid;
        const int k0 = kt * BKT;
        const int c0 = ct * 64;
        const int qb0 = qs * QPB;

        const int cc = t >> 2;
        const int j1 = t & 3;
        const int j2 = j1 + 4;
        const int c0l = (t >> 4) << 2;
        const int k0l = (t & 15) << 2;

        float acc[4][4];
#pragma unroll
        for (int i = 0; i < 4; ++i)
#pragma unroll
            for (int j = 0; j < 4; ++j) acc[i][j] = 0.0f;

        const float* vb = vg + ((size_t)b * kC + c0) * kN;
        const float* ab = attn + (size_t)b * kN * kN;
        const int krow_st = min(k0 + cc, kN - 1);

        for (int qc = 0; qc < QPB; qc += QCH) {
            const int q0 = qb0 + qc;
            const float4 vv1 = *reinterpret_cast<const float4*>(vb + (size_t)cc * kN + q0 + 4 * j1);
            const float4 av1 = *reinterpret_cast<const float4*>(ab + (size_t)krow_st * kN + q0 + 4 * j1);
            float4 vv2, av2;
            const bool has2 = (j2 < 7);
            if (has2) {
                vv2 = *reinterpret_cast<const float4*>(vb + (size_t)cc * kN + q0 + 4 * j2);
                av2 = *reinterpret_cast<const float4*>(ab + (size_t)krow_st * kN + q0 + 4 * j2);
            }
            __syncthreads();
            {
                const int r1 = 4 * j1;
                sh.m.vT[r1 + 0][cc] = vv1.x; sh.m.vT[r1 + 1][cc] = vv1.y;
                sh.m.vT[r1 + 2][cc] = vv1.z; sh.m.vT[r1 + 3][cc] = vv1.w;
                sh.m.aT[r1 + 0][cc] = av1.x; sh.m.aT[r1 + 1][cc] = av1.y;
                sh.m.aT[r1 + 2][cc] = av1.z; sh.m.aT[r1 + 3][cc] = av1.w;
                if (has2) {
                    const int r2 = 4 * j2;
                    sh.m.vT[r2 + 0][cc] = vv2.x; sh.m.vT[r2 + 1][cc] = vv2.y;
                    sh.m.vT[r2 + 2][cc] = vv2.z; sh.m.vT[r2 + 3][cc] = vv2.w;
                    sh.m.aT[r2 + 0][cc] = av2.x; sh.m.aT[r2 + 1][cc] = av2.y;
                    sh.m.aT[r2 + 2][cc] = av2.z; sh.m.aT[r2 + 3][cc] = av2.w;
                }
            }
            __syncthreads();

#pragma unroll
            for (int qq = 0; qq < QCH; ++qq) {
                const float4 vf4 = *reinterpret_cast<const float4*>(&sh.m.vT[qq][c0l]);
                const float4 af4 = *reinterpret_cast<const float4*>(&sh.m.aT[qq][k0l]);
                const float vf[4] = {vf4.x, vf4.y, vf4.z, vf4.w};
                const float af[4] = {af4.x, af4.y, af4.z, af4.w};
#pragma unroll
                for (int i = 0; i < 4; ++i)
#pragma unroll
                    for (int j = 0; j < 4; ++j) acc[i][j] += vf[i] * af[j];
            }
        }

        if (k0 + k0l < kN) {
#pragma unroll
            for (int i = 0; i < 4; ++i) {
                const int c = c0 + c0l + i;
                *reinterpret_cast<float4*>(
                    P + (((size_t)qs * kB + b) * kC + c) * kN + k0 + k0l) =
                    make_float4(acc[i][0], acc[i][1], acc[i][2], acc[i][3]);
            }
        }
        __syncthreads();
    }

    gbarrier(bar, 3u * GRID);

    // ================= Phase 4: out = sum_qs P[qs] =================
    for (int idx = (int)blockIdx.x * 256 + t; idx < (int)(kOutElems / 4); idx += GRID * 256) {
        const float4* p = reinterpret_cast<const float4*>(P) + idx;
        float4 s = p[0];
#pragma unroll
        for (int qs = 1; qs < QSP; ++qs) {
            const float4 v = p[(size_t)qs * (kOutElems / 4)];
            s.x += v.x; s.y += v.y; s.z += v.z; s.w += v.w;
        }
        reinterpret_cast<float4*>(out)[idx] = s;
    }
}

// ======================= Fallback path (ws too small; never expected) =======================
__global__ __launch_bounds__(256) void dist_fb(const float* __restrict__ qg,
                                               const float* __restrict__ kg,
                                               float* __restrict__ D0) {
    int bid = blockIdx.x;
    const int qt = bid % NQT; bid /= NQT;
    const int kt = bid % NKT; bid /= NKT;
    const int ch = bid & 1;   bid >>= 1;
    const int b  = bid;
    const int k0 = kt * TK, q0 = qt * TQ;
    const int t = threadIdx.x;
    __shared__ float ks[CH][DSTR];
    __shared__ float qs[CH][DSTR];
    const float* kb = kg + ((size_t)b * kC + ch * CH) * kN;
    const float* qb = qg + ((size_t)b * kC + ch * CH) * kN;
    for (int i = t; i < CH * 16; i += 256) {
        const int c = i >> 4, x4 = (i & 15) << 2;
        *reinterpret_cast<float4*>(&ks[c][x4]) =
            *reinterpret_cast<const float4*>(kb + (size_t)c * kN + min(k0 + x4, kN - 4));
        float4 qv = *reinterpret_cast<const float4*>(qb + (size_t)c * kN + min(q0 + x4, kN - 4));
        qv.x *= kInvT; qv.y *= kInvT; qv.z *= kInvT; qv.w *= kInvT;
        *reinterpret_cast<float4*>(&qs[c][x4]) = qv;
    }
    __syncthreads();
    const int qx = (t & 15) << 2, kx = (t >> 4) << 2;
    float acc[4][4];
    for (int i = 0; i < 4; ++i)
        for (int j = 0; j < 4; ++j) acc[i][j] = 0.0f;
    for (int c = 0; c < CH; ++c) {
        const float4 kv = *reinterpret_cast<const float4*>(&ks[c][kx]);
        const float4 qv = *reinterpret_cast<const float4*>(&qs[c][qx]);
        const float kf[4] = {kv.x, kv.y, kv.z, kv.w};
        const float qf[4] = {qv.x, qv.y, qv.z, qv.w};
        for (int i = 0; i < 4; ++i)
            for (int j = 0; j < 4; ++j) acc[i][j] += fabsf(qf[j] - kf[i]);
    }
    const int qcol = q0 + qx;
    if (qcol < kN)
        for (int i = 0; i < 4; ++i) {
            const int krow = k0 + kx + i;
            if (krow < kN) {
                const size_t off = ((size_t)b * kN + krow) * kN + qcol;
                atomicAdd(&D0[off + 0], acc[i][0]);
                atomicAdd(&D0[off + 1], acc[i][1]);
                atomicAdd(&D0[off + 2], acc[i][2]);
                atomicAdd(&D0[off + 3], acc[i][3]);
            }
        }
}

__global__ __launch_bounds__(256) void softmax_fb(float* __restrict__ A) {
    float4* A4 = reinterpret_cast<float4*>(A + (size_t)blockIdx.x * kN);
    const int t = threadIdx.x, lane = t & 63, wid = t >> 6;
    const bool act = t < (kN / 4);
    __shared__ float xred[4];
    float4 x = make_float4(-1e30f, -1e30f, -1e30f, -1e30f);
    if (act) x = A4[t];
    float m = fmaxf(fmaxf(x.x, x.y), fmaxf(x.z, x.w));
    m = wave_max(m);
    if (lane == 0) xred[wid] = m;
    __syncthreads();
    m = fmaxf(fmaxf(xred[0], xred[1]), fmaxf(xred[2], xred[3]));
    __syncthreads();
    float4 p;
    p.x = __expf((x.x - m) * kInvC); p.y = __expf((x.y - m) * kInvC);
    p.z = __expf((x.z - m) * kInvC); p.w = __expf((x.w - m) * kInvC);
    float ls = p.x + p.y + p.z + p.w;
    ls = wave_sum(ls);
    if (lane == 0) xred[wid] = ls;
    __syncthreads();
    const float inv = 1.0f / (xred[0] + xred[1] + xred[2] + xred[3]);
    if (act) { p.x *= inv; p.y *= inv; p.z *= inv; p.w *= inv; A4[t] = p; }
}

__global__ __launch_bounds__(256) void bmm_fb(const float* __restrict__ vg,
                                              const float* __restrict__ attn,
                                              float* __restrict__ out) {
    int bid = blockIdx.x;
    const int qs = bid % QSP;   bid /= QSP;
    const int kt = bid % NKT2;  bid /= NKT2;
    const int ct = bid & 1;     bid >>= 1;
    const int b  = bid;
    const int k0 = kt * BKT, c0 = ct * 64, qb0 = qs * QPB;
    const int t = threadIdx.x;
    __shared__ float vT[QCH][BSTR];
    __shared__ float aT[QCH][BSTR];
    const int cc = t >> 2, j1 = t & 3, j2 = j1 + 4;
    const int c0l = (t >> 4) << 2, k0l = (t & 15) << 2;
    float acc[4][4];
    for (int i = 0; i < 4; ++i)
        for (int j = 0; j < 4; ++j) acc[i][j] = 0.0f;
    const float* vb = vg + ((size_t)b * kC + c0) * kN;
    const float* ab = attn + (size_t)b * kN * kN;
    const int krow_st = min(k0 + cc, kN - 1);
    for (int qc = 0; qc < QPB; qc += QCH) {
        const int q0 = qb0 + qc;
        const float4 vv1 = *reinterpret_cast<const float4*>(vb + (size_t)cc * kN + q0 + 4 * j1);
        const float4 av1 = *reinterpret_cast<const float4*>(ab + (size_t)krow_st * kN + q0 + 4 * j1);
        float4 vv2, av2;
        const bool has2 = (j2 < 7);
        if (has2) {
            vv2 = *reinterpret_cast<const float4*>(vb + (size_t)cc * kN + q0 + 4 * j2);
            av2 = *reinterpret_cast<const float4*>(ab + (size_t)krow_st * kN + q0 + 4 * j2);
        }
        __syncthreads();
        const int r1 = 4 * j1;
        vT[r1 + 0][cc] = vv1.x; vT[r1 + 1][cc] = vv1.y;
        vT[r1 + 2][cc] = vv1.z; vT[r1 + 3][cc] = vv1.w;
        aT[r1 + 0][cc] = av1.x; aT[r1 + 1][cc] = av1.y;
        aT[r1 + 2][cc] = av1.z; aT[r1 + 3][cc] = av1.w;
        if (has2) {
            const int r2 = 4 * j2;
            vT[r2 + 0][cc] = vv2.x; vT[r2 + 1][cc] = vv2.y;
            vT[r2 + 2][cc] = vv2.z; vT[r2 + 3][cc] = vv2.w;
            aT[r2 + 0][cc] = av2.x; aT[r2 + 1][cc] = av2.y;
            aT[r2 + 2][cc] = av2.z; aT[r2 + 3][cc] = av2.w;
        }
        __syncthreads();
        for (int qq = 0; qq < QCH; ++qq) {
            const float4 vf4 = *reinterpret_cast<const float4*>(&vT[qq][c0l]);
            const float4 af4 = *reinterpret_cast<const float4*>(&aT[qq][k0l]);
            const float vf[4] = {vf4.x, vf4.y, vf4.z, vf4.w};
            const float af[4] = {af4.x, af4.y, af4.z, af4.w};
            for (int i = 0; i < 4; ++i)
                for (int j = 0; j < 4; ++j) acc[i][j] += vf[i] * af[j];
        }
    }
    for (int i = 0; i < 4; ++i) {
        const int c = c0 + c0l + i;
        for (int j = 0; j < 4; ++j) {
            const int krow = k0 + k0l + j;
            if (krow < kN)
                atomicAdd(&out[((size_t)b * kC + c) * kN + krow], acc[i][j]);
        }
    }
}

extern "C" void kernel_launch(void* const* d_in, const int* in_sizes, int n_in,
                              void* d_out, int out_size, void* d_ws, size_t ws_size,
                              hipStream_t stream) {
    const float* q = (const float*)d_in[0];
    const float* k = (const float*)d_in[1];
    const float* v = (const float*)d_in[2];

    float* out  = (float*)d_out;               // [B, C, N]
    float* attn = out + kOutElems;             // [B, N, N]
    float* P    = (float*)d_ws;                // [QSP][B, C, N] partials
    float* D1   = P + (size_t)QSP * kOutElems; // [B, N, N] second dist half
    unsigned* bar = (unsigned*)(D1 + kAttnElems);  // barrier counter (16 B)

    const size_t need = ((size_t)QSP * kOutElems + kAttnElems) * sizeof(float) + 64;

    if (ws_size >= need) {
        // zero the barrier counter (ws is re-poisoned to 0xAA before every call)
        hipMemsetAsync(bar, 0, 16, stream);
        mega_kernel<<<GRID, 256, 0, stream>>>(q, k, v, out, attn, P, D1, bar);
    } else {
        hipMemsetAsync(attn, 0, kAttnElems * sizeof(float), stream);
        hipMemsetAsync(out, 0, kOutElems * sizeof(float), stream);
        dist_fb<<<kB * CSP * NKT * NQT, 256, 0, stream>>>(q, k, attn);
        softmax_fb<<<NROWS, 256, 0, stream>>>(attn);
        bmm_fb<<<NBMM, 256, 0, stream>>>(v, attn, out);
    }
}

// Round 11
// 162.259 us; speedup vs baseline: 1.7429x; 1.7429x over previous
//
#include <hip/hip_runtime.h>
#include <math.h>

// Problem constants
constexpr int kB = 2;
constexpr int kC = 128;
constexpr int kN = 784;
constexpr float kInvT = 1.0f / 11.313708498984761f;  // 1/sqrt(C)
constexpr float kInvC = 1.0f / 128.0f;

constexpr size_t kOutElems  = (size_t)kB * kC * kN;  // 200704
constexpr size_t kAttnElems = (size_t)kB * kN * kN;  // 1229312

// dist tiling: 64k x 64q, c split in 2 halves; one tile per block.
constexpr int TK = 64, TQ = 64;
constexpr int NKT = 13, NQT = 13;
constexpr int CSP = 2, CH = 64;
constexpr int DSTR = 68;
constexpr int NDIST = kB * CSP * NKT * NQT;  // 676
constexpr int DGRP_MEMBERS = CSP * NQT;      // 26 tiles complete one (b,kt) row-group

// bmm tiling: 64c x 64k, qsplit 14 (56 q each, 2 chunks of 28); one tile per block.
constexpr int BKT = 64, NKT2 = 13;
constexpr int QSP = 14, QPB = 56, QCH = 28;
constexpr int BSTR = 68;
constexpr int NBMM = kB * 2 * NKT2 * QSP;  // 728

constexpr int NROWS = kB * kN;  // 1568 softmax rows (fallback)

__device__ inline float wave_max(float v) {
#pragma unroll
    for (int o = 32; o > 0; o >>= 1) v = fmaxf(v, __shfl_xor(v, o, 64));
    return v;
}
__device__ inline float wave_sum(float v) {
#pragma unroll
    for (int o = 32; o > 0; o >>= 1) v += __shfl_xor(v, o, 64);
    return v;
}

// ============ Kernel 1: dist tiles + last-block-per-(b,kt) fused softmax ============
// Each block: one 64k x 64q x 64c tile of D (half 0 -> attn region, half 1 -> ws),
// then an agent-scope acq-rel counter bump. The 26th arrival for a (b,kt) group
// softmaxes that group's 64 rows (wave-per-row, shfl-only), summing the c-halves.
// __syncthreads() before the bump drains vmcnt(0), so all block stores are in L2;
// the release writes back L2, the last block's acquire invalidates stale caches.
__global__ __launch_bounds__(256) void dist_sm(const float* __restrict__ qg,
                                               const float* __restrict__ kg,
                                               float* __restrict__ attn,
                                               float* __restrict__ D1,
                                               unsigned* __restrict__ cnt) {
    int bid = blockIdx.x;
    const int qt = bid % NQT; bid /= NQT;
    const int kt = bid % NKT; bid /= NKT;
    const int ch = bid & 1;   bid >>= 1;
    const int b  = bid;
    const int k0 = kt * TK;
    const int q0 = qt * TQ;
    const int t  = threadIdx.x;

    __shared__ float ks[CH][DSTR];  // 17.4 KB
    __shared__ float qs[CH][DSTR];  // 17.4 KB
    __shared__ int do_sm;

    const float* kb = kg + ((size_t)b * kC + ch * CH) * kN;
    const float* qb = qg + ((size_t)b * kC + ch * CH) * kN;

#pragma unroll
    for (int i = t; i < CH * 16; i += 256) {
        const int c  = i >> 4;
        const int x4 = (i & 15) << 2;
        *reinterpret_cast<float4*>(&ks[c][x4]) =
            *reinterpret_cast<const float4*>(kb + (size_t)c * kN + min(k0 + x4, kN - 4));
        float4 qv = *reinterpret_cast<const float4*>(qb + (size_t)c * kN + min(q0 + x4, kN - 4));
        qv.x *= kInvT; qv.y *= kInvT; qv.z *= kInvT; qv.w *= kInvT;
        *reinterpret_cast<float4*>(&qs[c][x4]) = qv;
    }
    __syncthreads();

    const int qx = (t & 15) << 2;
    const int kx = (t >> 4) << 2;

    float acc[4][4];
#pragma unroll
    for (int i = 0; i < 4; ++i)
#pragma unroll
        for (int j = 0; j < 4; ++j) acc[i][j] = 0.0f;

#pragma unroll 4
    for (int c = 0; c < CH; ++c) {
        const float4 kv = *reinterpret_cast<const float4*>(&ks[c][kx]);
        const float4 qv = *reinterpret_cast<const float4*>(&qs[c][qx]);
        const float kf[4] = {kv.x, kv.y, kv.z, kv.w};
        const float qf[4] = {qv.x, qv.y, qv.z, qv.w};
#pragma unroll
        for (int i = 0; i < 4; ++i)
#pragma unroll
            for (int j = 0; j < 4; ++j)
                acc[i][j] += fabsf(qf[j] - kf[i]);
    }

    const int qcol = q0 + qx;
    if (qcol < kN) {
        float* dst = ch ? D1 : attn;
#pragma unroll
        for (int i = 0; i < 4; ++i) {
            const int krow = k0 + kx + i;
            if (krow < kN) {
                *reinterpret_cast<float4*>(&dst[((size_t)b * kN + krow) * kN + qcol]) =
                    make_float4(acc[i][0], acc[i][1], acc[i][2], acc[i][3]);
            }
        }
    }

    // ---- completion counter: last of 26 tiles softmaxes the 64-row group ----
    __syncthreads();  // drains vmcnt -> all block stores complete before the bump
    if (t == 0) {
        const unsigned prev = __hip_atomic_fetch_add(&cnt[b * NKT + kt], 1u,
                                                     __ATOMIC_ACQ_REL,
                                                     __HIP_MEMORY_SCOPE_AGENT);
        do_sm = (prev == DGRP_MEMBERS - 1);
    }
    __syncthreads();

    if (do_sm) {
        const int wid = t >> 6, lane = t & 63;
        const bool h3 = lane < 4;  // 196 = 3*64 + 4 float4 chunks per row
        for (int r = wid; r < TK; r += 4) {
            const int krow = k0 + r;
            if (krow >= kN) continue;
            const size_t row = ((size_t)b * kN + krow) * kN;
            float4* A4 = reinterpret_cast<float4*>(attn + row);
            const float4* W4 = reinterpret_cast<const float4*>(D1 + row);

            float4 x0 = A4[lane],       w0 = W4[lane];
            float4 x1 = A4[lane + 64],  w1 = W4[lane + 64];
            float4 x2 = A4[lane + 128], w2 = W4[lane + 128];
            float4 x3 = make_float4(-1e30f, -1e30f, -1e30f, -1e30f);
            if (h3) {
                const float4 a3 = A4[lane + 192], w3 = W4[lane + 192];
                x3 = make_float4(a3.x + w3.x, a3.y + w3.y, a3.z + w3.z, a3.w + w3.w);
            }
            x0.x += w0.x; x0.y += w0.y; x0.z += w0.z; x0.w += w0.w;
            x1.x += w1.x; x1.y += w1.y; x1.z += w1.z; x1.w += w1.w;
            x2.x += w2.x; x2.y += w2.y; x2.z += w2.z; x2.w += w2.w;

            float m = fmaxf(fmaxf(fmaxf(x0.x, x0.y), fmaxf(x0.z, x0.w)),
                            fmaxf(fmaxf(x1.x, x1.y), fmaxf(x1.z, x1.w)));
            m = fmaxf(m, fmaxf(fmaxf(x2.x, x2.y), fmaxf(x2.z, x2.w)));
            m = fmaxf(m, fmaxf(fmaxf(x3.x, x3.y), fmaxf(x3.z, x3.w)));
            m = wave_max(m);

            float4 p0, p1, p2, p3;
            p0.x = __expf((x0.x - m) * kInvC); p0.y = __expf((x0.y - m) * kInvC);
            p0.z = __expf((x0.z - m) * kInvC); p0.w = __expf((x0.w - m) * kInvC);
            p1.x = __expf((x1.x - m) * kInvC); p1.y = __expf((x1.y - m) * kInvC);
            p1.z = __expf((x1.z - m) * kInvC); p1.w = __expf((x1.w - m) * kInvC);
            p2.x = __expf((x2.x - m) * kInvC); p2.y = __expf((x2.y - m) * kInvC);
            p2.z = __expf((x2.z - m) * kInvC); p2.w = __expf((x2.w - m) * kInvC);
            p3.x = __expf((x3.x - m) * kInvC); p3.y = __expf((x3.y - m) * kInvC);
            p3.z = __expf((x3.z - m) * kInvC); p3.w = __expf((x3.w - m) * kInvC);

            float s = p0.x + p0.y + p0.z + p0.w + p1.x + p1.y + p1.z + p1.w +
                      p2.x + p2.y + p2.z + p2.w + p3.x + p3.y + p3.z + p3.w;
            s = wave_sum(s);
            const float inv = 1.0f / s;

            p0.x *= inv; p0.y *= inv; p0.z *= inv; p0.w *= inv;
            p1.x *= inv; p1.y *= inv; p1.z *= inv; p1.w *= inv;
            p2.x *= inv; p2.y *= inv; p2.z *= inv; p2.w *= inv;
            A4[lane] = p0; A4[lane + 64] = p1; A4[lane + 128] = p2;
            if (h3) {
                p3.x *= inv; p3.y *= inv; p3.z *= inv; p3.w *= inv;
                A4[lane + 192] = p3;
            }
        }
    }
}

// ============ Kernel 2: bmm partials + last-block-per-(b,ct,kt) fused reduce ============
// Each block: one 64c x 64k x 56q partial into P[qs] (clean float4 stores), then a
// counter bump; the 14th arrival sums the 14 qs slabs and writes out.
__global__ __launch_bounds__(256) void bmm_red(const float* __restrict__ vg,
                                               const float* __restrict__ attn,
                                               float* __restrict__ P,
                                               float* __restrict__ out,
                                               unsigned* __restrict__ cnt) {
    int bid = blockIdx.x;
    const int qs = bid % QSP;   bid /= QSP;
    const int kt = bid % NKT2;  bid /= NKT2;
    const int ct = bid & 1;     bid >>= 1;
    const int b  = bid;
    const int k0 = kt * BKT;
    const int c0 = ct * 64;
    const int qb0 = qs * QPB;
    const int t  = threadIdx.x;

    __shared__ float vT[QCH][BSTR];
    __shared__ float aT[QCH][BSTR];
    __shared__ int do_red;

    const int cc = t >> 2;
    const int j1 = t & 3;
    const int j2 = j1 + 4;
    const int c0l = (t >> 4) << 2;  // c: wave-broadcast reads
    const int k0l = (t & 15) << 2;  // k: lane-fast (coalesced stores)

    float acc[4][4];
#pragma unroll
    for (int i = 0; i < 4; ++i)
#pragma unroll
        for (int j = 0; j < 4; ++j) acc[i][j] = 0.0f;

    const float* vb = vg + ((size_t)b * kC + c0) * kN;
    const float* ab = attn + (size_t)b * kN * kN;
    const int krow_st = min(k0 + cc, kN - 1);

    for (int qc = 0; qc < QPB; qc += QCH) {
        const int q0 = qb0 + qc;
        const float4 vv1 = *reinterpret_cast<const float4*>(vb + (size_t)cc * kN + q0 + 4 * j1);
        const float4 av1 = *reinterpret_cast<const float4*>(ab + (size_t)krow_st * kN + q0 + 4 * j1);
        float4 vv2, av2;
        const bool has2 = (j2 < 7);
        if (has2) {
            vv2 = *reinterpret_cast<const float4*>(vb + (size_t)cc * kN + q0 + 4 * j2);
            av2 = *reinterpret_cast<const float4*>(ab + (size_t)krow_st * kN + q0 + 4 * j2);
        }
        __syncthreads();
        {
            const int r1 = 4 * j1;
            vT[r1 + 0][cc] = vv1.x; vT[r1 + 1][cc] = vv1.y;
            vT[r1 + 2][cc] = vv1.z; vT[r1 + 3][cc] = vv1.w;
            aT[r1 + 0][cc] = av1.x; aT[r1 + 1][cc] = av1.y;
            aT[r1 + 2][cc] = av1.z; aT[r1 + 3][cc] = av1.w;
            if (has2) {
                const int r2 = 4 * j2;
                vT[r2 + 0][cc] = vv2.x; vT[r2 + 1][cc] = vv2.y;
                vT[r2 + 2][cc] = vv2.z; vT[r2 + 3][cc] = vv2.w;
                aT[r2 + 0][cc] = av2.x; aT[r2 + 1][cc] = av2.y;
                aT[r2 + 2][cc] = av2.z; aT[r2 + 3][cc] = av2.w;
            }
        }
        __syncthreads();

#pragma unroll
        for (int qq = 0; qq < QCH; ++qq) {
            const float4 vf4 = *reinterpret_cast<const float4*>(&vT[qq][c0l]);
            const float4 af4 = *reinterpret_cast<const float4*>(&aT[qq][k0l]);
            const float vf[4] = {vf4.x, vf4.y, vf4.z, vf4.w};
            const float af[4] = {af4.x, af4.y, af4.z, af4.w};
#pragma unroll
            for (int i = 0; i < 4; ++i)
#pragma unroll
                for (int j = 0; j < 4; ++j) acc[i][j] += vf[i] * af[j];
        }
    }

    if (k0 + k0l < kN) {  // kN%4==0: float4 fully valid or fully out
#pragma unroll
        for (int i = 0; i < 4; ++i) {
            const int c = c0 + c0l + i;
            *reinterpret_cast<float4*>(
                P + (((size_t)qs * kB + b) * kC + c) * kN + k0 + k0l) =
                make_float4(acc[i][0], acc[i][1], acc[i][2], acc[i][3]);
        }
    }

    // ---- completion counter: last of 14 qs partials reduces the slab ----
    __syncthreads();  // drain vmcnt: partial stores complete before the bump
    if (t == 0) {
        const unsigned prev = __hip_atomic_fetch_add(&cnt[(b * 2 + ct) * NKT2 + kt], 1u,
                                                     __ATOMIC_ACQ_REL,
                                                     __HIP_MEMORY_SCOPE_AGENT);
        do_red = (prev == QSP - 1);
    }
    __syncthreads();

    if (do_red) {
        for (int it = t; it < 64 * 16; it += 256) {  // 64 c x 16 k-float4 groups
            const int c  = it >> 4;
            const int kk = k0 + ((it & 15) << 2);
            if (kk >= kN) continue;
            float4 s = make_float4(0.f, 0.f, 0.f, 0.f);
#pragma unroll
            for (int q = 0; q < QSP; ++q) {
                const float4 v = *reinterpret_cast<const float4*>(
                    P + (((size_t)q * kB + b) * kC + (c0 + c)) * kN + kk);
                s.x += v.x; s.y += v.y; s.z += v.z; s.w += v.w;
            }
            *reinterpret_cast<float4*>(out + ((size_t)b * kC + (c0 + c)) * kN + kk) = s;
        }
    }
}

// ======================= Fallback path (ws too small; never expected) =======================
__global__ __launch_bounds__(256) void dist_fb(const float* __restrict__ qg,
                                               const float* __restrict__ kg,
                                               float* __restrict__ D0) {
    int bid = blockIdx.x;
    const int qt = bid % NQT; bid /= NQT;
    const int kt = bid % NKT; bid /= NKT;
    const int ch = bid & 1;   bid >>= 1;
    const int b  = bid;
    const int k0 = kt * TK, q0 = qt * TQ;
    const int t = threadIdx.x;
    __shared__ float ks[CH][DSTR];
    __shared__ float qs[CH][DSTR];
    const float* kb = kg + ((size_t)b * kC + ch * CH) * kN;
    const float* qb = qg + ((size_t)b * kC + ch * CH) * kN;
    for (int i = t; i < CH * 16; i += 256) {
        const int c = i >> 4, x4 = (i & 15) << 2;
        *reinterpret_cast<float4*>(&ks[c][x4]) =
            *reinterpret_cast<const float4*>(kb + (size_t)c * kN + min(k0 + x4, kN - 4));
        float4 qv = *reinterpret_cast<const float4*>(qb + (size_t)c * kN + min(q0 + x4, kN - 4));
        qv.x *= kInvT; qv.y *= kInvT; qv.z *= kInvT; qv.w *= kInvT;
        *reinterpret_cast<float4*>(&qs[c][x4]) = qv;
    }
    __syncthreads();
    const int qx = (t & 15) << 2, kx = (t >> 4) << 2;
    float acc[4][4];
    for (int i = 0; i < 4; ++i)
        for (int j = 0; j < 4; ++j) acc[i][j] = 0.0f;
    for (int c = 0; c < CH; ++c) {
        const float4 kv = *reinterpret_cast<const float4*>(&ks[c][kx]);
        const float4 qv = *reinterpret_cast<const float4*>(&qs[c][qx]);
        const float kf[4] = {kv.x, kv.y, kv.z, kv.w};
        const float qf[4] = {qv.x, qv.y, qv.z, qv.w};
        for (int i = 0; i < 4; ++i)
            for (int j = 0; j < 4; ++j) acc[i][j] += fabsf(qf[j] - kf[i]);
    }
    const int qcol = q0 + qx;
    if (qcol < kN)
        for (int i = 0; i < 4; ++i) {
            const int krow = k0 + kx + i;
            if (krow < kN) {
                const size_t off = ((size_t)b * kN + krow) * kN + qcol;
                atomicAdd(&D0[off + 0], acc[i][0]);
                atomicAdd(&D0[off + 1], acc[i][1]);
                atomicAdd(&D0[off + 2], acc[i][2]);
                atomicAdd(&D0[off + 3], acc[i][3]);
            }
        }
}

__global__ __launch_bounds__(256) void softmax_fb(float* __restrict__ A) {
    float4* A4 = reinterpret_cast<float4*>(A + (size_t)blockIdx.x * kN);
    const int t = threadIdx.x, lane = t & 63, wid = t >> 6;
    const bool act = t < (kN / 4);
    __shared__ float xred[4];
    float4 x = make_float4(-1e30f, -1e30f, -1e30f, -1e30f);
    if (act) x = A4[t];
    float m = fmaxf(fmaxf(x.x, x.y), fmaxf(x.z, x.w));
    m = wave_max(m);
    if (lane == 0) xred[wid] = m;
    __syncthreads();
    m = fmaxf(fmaxf(xred[0], xred[1]), fmaxf(xred[2], xred[3]));
    __syncthreads();
    float4 p;
    p.x = __expf((x.x - m) * kInvC); p.y = __expf((x.y - m) * kInvC);
    p.z = __expf((x.z - m) * kInvC); p.w = __expf((x.w - m) * kInvC);
    float ls = p.x + p.y + p.z + p.w;
    ls = wave_sum(ls);
    if (lane == 0) xred[wid] = ls;
    __syncthreads();
    const float inv = 1.0f / (xred[0] + xred[1] + xred[2] + xred[3]);
    if (act) { p.x *= inv; p.y *= inv; p.z *= inv; p.w *= inv; A4[t] = p; }
}

__global__ __launch_bounds__(256) void bmm_fb(const float* __restrict__ vg,
                                              const float* __restrict__ attn,
                                              float* __restrict__ out) {
    int bid = blockIdx.x;
    const int qs = bid % QSP;   bid /= QSP;
    const int kt = bid % NKT2;  bid /= NKT2;
    const int ct = bid & 1;     bid >>= 1;
    const int b  = bid;
    const int k0 = kt * BKT, c0 = ct * 64, qb0 = qs * QPB;
    const int t = threadIdx.x;
    __shared__ float vT[QCH][BSTR];
    __shared__ float aT[QCH][BSTR];
    const int cc = t >> 2, j1 = t & 3, j2 = j1 + 4;
    const int c0l = (t >> 4) << 2, k0l = (t & 15) << 2;
    float acc[4][4];
    for (int i = 0; i < 4; ++i)
        for (int j = 0; j < 4; ++j) acc[i][j] = 0.0f;
    const float* vb = vg + ((size_t)b * kC + c0) * kN;
    const float* ab = attn + (size_t)b * kN * kN;
    const int krow_st = min(k0 + cc, kN - 1);
    for (int qc = 0; qc < QPB; qc += QCH) {
        const int q0 = qb0 + qc;
        const float4 vv1 = *reinterpret_cast<const float4*>(vb + (size_t)cc * kN + q0 + 4 * j1);
        const float4 av1 = *reinterpret_cast<const float4*>(ab + (size_t)krow_st * kN + q0 + 4 * j1);
        float4 vv2, av2;
        const bool has2 = (j2 < 7);
        if (has2) {
            vv2 = *reinterpret_cast<const float4*>(vb + (size_t)cc * kN + q0 + 4 * j2);
            av2 = *reinterpret_cast<const float4*>(ab + (size_t)krow_st * kN + q0 + 4 * j2);
        }
        __syncthreads();
        const int r1 = 4 * j1;
        vT[r1 + 0][cc] = vv1.x; vT[r1 + 1][cc] = vv1.y;
        vT[r1 + 2][cc] = vv1.z; vT[r1 + 3][cc] = vv1.w;
        aT[r1 + 0][cc] = av1.x; aT[r1 + 1][cc] = av1.y;
        aT[r1 + 2][cc] = av1.z; aT[r1 + 3][cc] = av1.w;
        if (has2) {
            const int r2 = 4 * j2;
            vT[r2 + 0][cc] = vv2.x; vT[r2 + 1][cc] = vv2.y;
            vT[r2 + 2][cc] = vv2.z; vT[r2 + 3][cc] = vv2.w;
            aT[r2 + 0][cc] = av2.x; aT[r2 + 1][cc] = av2.y;
            aT[r2 + 2][cc] = av2.z; aT[r2 + 3][cc] = av2.w;
        }
        __syncthreads();
        for (int qq = 0; qq < QCH; ++qq) {
            const float4 vf4 = *reinterpret_cast<const float4*>(&vT[qq][c0l]);
            const float4 af4 = *reinterpret_cast<const float4*>(&aT[qq][k0l]);
            const float vf[4] = {vf4.x, vf4.y, vf4.z, vf4.w};
            const float af[4] = {af4.x, af4.y, af4.z, af4.w};
            for (int i = 0; i < 4; ++i)
                for (int j = 0; j < 4; ++j) acc[i][j] += vf[i] * af[j];
        }
    }
    for (int i = 0; i < 4; ++i) {
        const int c = c0 + c0l + i;
        for (int j = 0; j < 4; ++j) {
            const int krow = k0 + k0l + j;
            if (krow < kN)
                atomicAdd(&out[((size_t)b * kC + c) * kN + krow], acc[i][j]);
        }
    }
}

extern "C" void kernel_launch(void* const* d_in, const int* in_sizes, int n_in,
                              void* d_out, int out_size, void* d_ws, size_t ws_size,
                              hipStream_t stream) {
    const float* q = (const float*)d_in[0];
    const float* k = (const float*)d_in[1];
    const float* v = (const float*)d_in[2];

    float* out  = (float*)d_out;               // [B, C, N]
    float* attn = out + kOutElems;             // [B, N, N]
    float* P    = (float*)d_ws;                // [QSP][B, C, N] partials
    float* D1   = P + (size_t)QSP * kOutElems; // [B, N, N] second dist half
    unsigned* cnt_d = (unsigned*)(D1 + kAttnElems);  // 26 dist-group counters
    unsigned* cnt_b = cnt_d + 32;                    // 52 bmm-group counters

    const size_t need = ((size_t)QSP * kOutElems + kAttnElems) * sizeof(float) + 512;

    if (ws_size >= need) {
        hipMemsetAsync(cnt_d, 0, 512, stream);  // counters re-poisoned 0xAA each call
        dist_sm<<<NDIST, 256, 0, stream>>>(q, k, attn, D1, cnt_d);
        bmm_red<<<NBMM, 256, 0, stream>>>(v, attn, P, out, cnt_b);
    } else {
        hipMemsetAsync(attn, 0, kAttnElems * sizeof(float), stream);
        hipMemsetAsync(out, 0, kOutElems * sizeof(float), stream);
        dist_fb<<<NDIST, 256, 0, stream>>>(q, k, attn);
        softmax_fb<<<NROWS, 256, 0, stream>>>(attn);
        bmm_fb<<<NBMM, 256, 0, stream>>>(v, attn, out);
    }
}

// Round 12
// 93.223 us; speedup vs baseline: 3.0336x; 1.7405x over previous
//
#include <hip/hip_runtime.h>
#include <math.h>

// Problem constants
constexpr int kB = 2;
constexpr int kC = 128;
constexpr int kN = 784;
constexpr float kInvT = 1.0f / 11.313708498984761f;  // 1/sqrt(C)
constexpr float kInvC = 1.0f / 128.0f;

constexpr size_t kOutElems  = (size_t)kB * kC * kN;  // 200704
constexpr size_t kAttnElems = (size_t)kB * kN * kN;  // 1229312

// dist tiling: 64k x 64q, c split in 2 halves; one tile per block.
constexpr int TK = 64, TQ = 64;
constexpr int NKT = 13, NQT = 13;
constexpr int CSP = 2, CH = 64;
constexpr int DSTR = 68;
constexpr int NDIST = kB * CSP * NKT * NQT;  // 676

// bmm tiling: 64c x 64k, qsplit 14 (56 q each, 2 chunks of 28); one tile per block.
constexpr int BKT = 64, NKT2 = 13;
constexpr int QSP = 14, QPB = 56, QCH = 28;
constexpr int BSTR = 68;
constexpr int NBMM = kB * 2 * NKT2 * QSP;  // 728

constexpr int NROWS = kB * kN;  // 1568 softmax rows

__device__ inline float wave_max(float v) {
#pragma unroll
    for (int o = 32; o > 0; o >>= 1) v = fmaxf(v, __shfl_xor(v, o, 64));
    return v;
}
__device__ inline float wave_sum(float v) {
#pragma unroll
    for (int o = 32; o > 0; o >>= 1) v += __shfl_xor(v, o, 64);
    return v;
}

// ================= Kernel 1: D[b,k,q] = sum_c |q[c,q]/T - k[c,k]| (raw sums) =================
// 64k x 64q tile, 4k x 4q per thread, c split in 2 halves. LDS 34.8 KB.
// Grid = 2b * 2ch * 13 * 13 = 676. Half 0 -> attn region, half 1 -> ws.
template <bool USE_WS>
__global__ __launch_bounds__(256) void dist_kernel(const float* __restrict__ qg,
                                                   const float* __restrict__ kg,
                                                   float* __restrict__ D0,
                                                   float* __restrict__ D1) {
    int bid = blockIdx.x;
    const int qt = bid % NQT; bid /= NQT;
    const int kt = bid % NKT; bid /= NKT;
    const int ch = bid & 1;   bid >>= 1;
    const int b  = bid;
    const int k0 = kt * TK;
    const int q0 = qt * TQ;
    const int t  = threadIdx.x;

    __shared__ float ks[CH][DSTR];  // 17.4 KB
    __shared__ float qs[CH][DSTR];  // 17.4 KB

    const float* kb = kg + ((size_t)b * kC + ch * CH) * kN;
    const float* qb = qg + ((size_t)b * kC + ch * CH) * kN;

#pragma unroll
    for (int i = t; i < CH * 16; i += 256) {
        const int c  = i >> 4;
        const int x4 = (i & 15) << 2;
        *reinterpret_cast<float4*>(&ks[c][x4]) =
            *reinterpret_cast<const float4*>(kb + (size_t)c * kN + min(k0 + x4, kN - 4));
        float4 qv = *reinterpret_cast<const float4*>(qb + (size_t)c * kN + min(q0 + x4, kN - 4));
        qv.x *= kInvT; qv.y *= kInvT; qv.z *= kInvT; qv.w *= kInvT;
        *reinterpret_cast<float4*>(&qs[c][x4]) = qv;
    }
    __syncthreads();

    const int qx = (t & 15) << 2;  // 16 q-groups (b128, 2-way = free)
    const int kx = (t >> 4) << 2;  // 16 k-groups (b128, 16-lane broadcast)

    float acc[4][4];
#pragma unroll
    for (int i = 0; i < 4; ++i)
#pragma unroll
        for (int j = 0; j < 4; ++j) acc[i][j] = 0.0f;

#pragma unroll 4
    for (int c = 0; c < CH; ++c) {
        const float4 kv = *reinterpret_cast<const float4*>(&ks[c][kx]);
        const float4 qv = *reinterpret_cast<const float4*>(&qs[c][qx]);
        const float kf[4] = {kv.x, kv.y, kv.z, kv.w};
        const float qf[4] = {qv.x, qv.y, qv.z, qv.w};
#pragma unroll
        for (int i = 0; i < 4; ++i)
#pragma unroll
            for (int j = 0; j < 4; ++j)
                acc[i][j] += fabsf(qf[j] - kf[i]);
    }

    const int qcol = q0 + qx;
    if (qcol < kN) {
        float* dst = (USE_WS && ch) ? D1 : D0;
#pragma unroll
        for (int i = 0; i < 4; ++i) {
            const int krow = k0 + kx + i;
            if (krow < kN) {
                const size_t off = ((size_t)b * kN + krow) * kN + qcol;
                if (USE_WS) {
                    *reinterpret_cast<float4*>(dst + off) =
                        make_float4(acc[i][0], acc[i][1], acc[i][2], acc[i][3]);
                } else {
                    atomicAdd(&D0[off + 0], acc[i][0]);
                    atomicAdd(&D0[off + 1], acc[i][1]);
                    atomicAdd(&D0[off + 2], acc[i][2]);
                    atomicAdd(&D0[off + 3], acc[i][3]);
                }
            }
        }
    }
}

// ================= Kernel 2: softmax, one wave per row (no LDS, shfl only) =================
// Grid 392 x 256 = 1568 waves; wave w handles row blockIdx.x*4+w. Sums the two
// c-halves (A += W), softmaxes over q with mean folded via kInvC.
template <bool SUM2>
__global__ __launch_bounds__(256) void softmax_wave(float* __restrict__ A,
                                                    const float* __restrict__ W) {
    const int wid = threadIdx.x >> 6, lane = threadIdx.x & 63;
    const int r = (int)blockIdx.x * 4 + wid;
    if (r >= NROWS) return;
    const size_t off = (size_t)r * kN;
    float4* A4 = reinterpret_cast<float4*>(A + off);
    const float4* W4 = reinterpret_cast<const float4*>(W + off);
    const bool h3 = lane < 4;  // 196 = 3*64 + 4 float4 chunks

    float4 x0 = A4[lane];
    float4 x1 = A4[lane + 64];
    float4 x2 = A4[lane + 128];
    float4 x3 = make_float4(-1e30f, -1e30f, -1e30f, -1e30f);
    if (SUM2) {
        const float4 w0 = W4[lane], w1 = W4[lane + 64], w2 = W4[lane + 128];
        x0.x += w0.x; x0.y += w0.y; x0.z += w0.z; x0.w += w0.w;
        x1.x += w1.x; x1.y += w1.y; x1.z += w1.z; x1.w += w1.w;
        x2.x += w2.x; x2.y += w2.y; x2.z += w2.z; x2.w += w2.w;
        if (h3) {
            const float4 a3 = A4[lane + 192], w3 = W4[lane + 192];
            x3 = make_float4(a3.x + w3.x, a3.y + w3.y, a3.z + w3.z, a3.w + w3.w);
        }
    } else if (h3) {
        x3 = A4[lane + 192];
    }

    float m = fmaxf(fmaxf(fmaxf(x0.x, x0.y), fmaxf(x0.z, x0.w)),
                    fmaxf(fmaxf(x1.x, x1.y), fmaxf(x1.z, x1.w)));
    m = fmaxf(m, fmaxf(fmaxf(x2.x, x2.y), fmaxf(x2.z, x2.w)));
    m = fmaxf(m, fmaxf(fmaxf(x3.x, x3.y), fmaxf(x3.z, x3.w)));
    m = wave_max(m);

    float4 p0, p1, p2, p3;
    p0.x = __expf((x0.x - m) * kInvC); p0.y = __expf((x0.y - m) * kInvC);
    p0.z = __expf((x0.z - m) * kInvC); p0.w = __expf((x0.w - m) * kInvC);
    p1.x = __expf((x1.x - m) * kInvC); p1.y = __expf((x1.y - m) * kInvC);
    p1.z = __expf((x1.z - m) * kInvC); p1.w = __expf((x1.w - m) * kInvC);
    p2.x = __expf((x2.x - m) * kInvC); p2.y = __expf((x2.y - m) * kInvC);
    p2.z = __expf((x2.z - m) * kInvC); p2.w = __expf((x2.w - m) * kInvC);
    p3.x = __expf((x3.x - m) * kInvC); p3.y = __expf((x3.y - m) * kInvC);
    p3.z = __expf((x3.z - m) * kInvC); p3.w = __expf((x3.w - m) * kInvC);

    float s = p0.x + p0.y + p0.z + p0.w + p1.x + p1.y + p1.z + p1.w +
              p2.x + p2.y + p2.z + p2.w + p3.x + p3.y + p3.z + p3.w;
    s = wave_sum(s);
    const float inv = 1.0f / s;

    p0.x *= inv; p0.y *= inv; p0.z *= inv; p0.w *= inv;
    p1.x *= inv; p1.y *= inv; p1.z *= inv; p1.w *= inv;
    p2.x *= inv; p2.y *= inv; p2.z *= inv; p2.w *= inv;
    A4[lane] = p0; A4[lane + 64] = p1; A4[lane + 128] = p2;
    if (h3) {
        p3.x *= inv; p3.y *= inv; p3.z *= inv; p3.w *= inv;
        A4[lane + 192] = p3;
    }
}

// ================= Kernel 3: partial[qs][b,c,k] = sum_{q in slice} v[b,c,q]*attn[b,k,q] =================
// 64c x 64k tile, 4c x 4k per thread, qsplit 14. Grid 728. Clean float4 partial
// stores (k lane-fast, coalesced). ATOMIC=true is the small-ws fallback.
template <bool ATOMIC>
__global__ __launch_bounds__(256) void bmm_stage1(const float* __restrict__ vg,
                                                  const float* __restrict__ attn,
                                                  float* __restrict__ P) {
    int bid = blockIdx.x;
    const int qs = bid % QSP;   bid /= QSP;
    const int kt = bid % NKT2;  bid /= NKT2;
    const int ct = bid & 1;     bid >>= 1;
    const int b  = bid;
    const int k0 = kt * BKT;
    const int c0 = ct * 64;
    const int qb0 = qs * QPB;
    const int t  = threadIdx.x;

    __shared__ float vT[QCH][BSTR];
    __shared__ float aT[QCH][BSTR];

    const int cc = t >> 2;          // staging row 0..63
    const int j1 = t & 3;           // q-float4 group 0..3
    const int j2 = j1 + 4;          // 4..6 valid
    const int c0l = (t >> 4) << 2;  // c: wave-broadcast reads
    const int k0l = (t & 15) << 2;  // k: lane-fast (coalesced stores)

    float acc[4][4];
#pragma unroll
    for (int i = 0; i < 4; ++i)
#pragma unroll
        for (int j = 0; j < 4; ++j) acc[i][j] = 0.0f;

    const float* vb = vg + ((size_t)b * kC + c0) * kN;
    const float* ab = attn + (size_t)b * kN * kN;
    const int krow_st = min(k0 + cc, kN - 1);  // clamped junk rows never stored

    for (int qc = 0; qc < QPB; qc += QCH) {
        const int q0 = qb0 + qc;
        const float4 vv1 = *reinterpret_cast<const float4*>(vb + (size_t)cc * kN + q0 + 4 * j1);
        const float4 av1 = *reinterpret_cast<const float4*>(ab + (size_t)krow_st * kN + q0 + 4 * j1);
        float4 vv2, av2;
        const bool has2 = (j2 < 7);
        if (has2) {
            vv2 = *reinterpret_cast<const float4*>(vb + (size_t)cc * kN + q0 + 4 * j2);
            av2 = *reinterpret_cast<const float4*>(ab + (size_t)krow_st * kN + q0 + 4 * j2);
        }
        __syncthreads();
        {
            const int r1 = 4 * j1;
            vT[r1 + 0][cc] = vv1.x; vT[r1 + 1][cc] = vv1.y;
            vT[r1 + 2][cc] = vv1.z; vT[r1 + 3][cc] = vv1.w;
            aT[r1 + 0][cc] = av1.x; aT[r1 + 1][cc] = av1.y;
            aT[r1 + 2][cc] = av1.z; aT[r1 + 3][cc] = av1.w;
            if (has2) {
                const int r2 = 4 * j2;
                vT[r2 + 0][cc] = vv2.x; vT[r2 + 1][cc] = vv2.y;
                vT[r2 + 2][cc] = vv2.z; vT[r2 + 3][cc] = vv2.w;
                aT[r2 + 0][cc] = av2.x; aT[r2 + 1][cc] = av2.y;
                aT[r2 + 2][cc] = av2.z; aT[r2 + 3][cc] = av2.w;
            }
        }
        __syncthreads();

#pragma unroll
        for (int qq = 0; qq < QCH; ++qq) {
            const float4 vf4 = *reinterpret_cast<const float4*>(&vT[qq][c0l]);
            const float4 af4 = *reinterpret_cast<const float4*>(&aT[qq][k0l]);
            const float vf[4] = {vf4.x, vf4.y, vf4.z, vf4.w};
            const float af[4] = {af4.x, af4.y, af4.z, af4.w};
#pragma unroll
            for (int i = 0; i < 4; ++i)
#pragma unroll
                for (int j = 0; j < 4; ++j) acc[i][j] += vf[i] * af[j];
        }
    }

    if (ATOMIC) {
#pragma unroll
        for (int i = 0; i < 4; ++i) {
            const int c = c0 + c0l + i;
#pragma unroll
            for (int j = 0; j < 4; ++j) {
                const int krow = k0 + k0l + j;
                if (krow < kN)
                    atomicAdd(&P[((size_t)b * kC + c) * kN + krow], acc[i][j]);
            }
        }
    } else if (k0 + k0l < kN) {  // kN%4==0: float4 fully valid or fully out
#pragma unroll
        for (int i = 0; i < 4; ++i) {
            const int c = c0 + c0l + i;
            *reinterpret_cast<float4*>(
                P + (((size_t)qs * kB + b) * kC + c) * kN + k0 + k0l) =
                make_float4(acc[i][0], acc[i][1], acc[i][2], acc[i][3]);
        }
    }
}

// ================= Kernel 4: out = sum_qs partial[qs] =================
__global__ __launch_bounds__(256) void reduce_kernel(const float* __restrict__ P,
                                                     float* __restrict__ out) {
    const int idx = blockIdx.x * 256 + threadIdx.x;  // < 50176 exactly
    const float4* p = reinterpret_cast<const float4*>(P) + idx;
    float4 s = p[0];
#pragma unroll
    for (int qs = 1; qs < QSP; ++qs) {
        const float4 v = p[(size_t)qs * (kOutElems / 4)];
        s.x += v.x; s.y += v.y; s.z += v.z; s.w += v.w;
    }
    reinterpret_cast<float4*>(out)[idx] = s;
}

extern "C" void kernel_launch(void* const* d_in, const int* in_sizes, int n_in,
                              void* d_out, int out_size, void* d_ws, size_t ws_size,
                              hipStream_t stream) {
    const float* q = (const float*)d_in[0];
    const float* k = (const float*)d_in[1];
    const float* v = (const float*)d_in[2];

    float* out  = (float*)d_out;               // [B, C, N]
    float* attn = out + kOutElems;             // [B, N, N]
    float* P    = (float*)d_ws;                // [QSP][B, C, N] partials
    float* D1   = P + (size_t)QSP * kOutElems; // [B, N, N] second dist half

    const size_t need = ((size_t)QSP * kOutElems + kAttnElems) * sizeof(float);

    if (ws_size >= need) {
        dist_kernel<true><<<NDIST, 256, 0, stream>>>(q, k, attn, D1);
        softmax_wave<true><<<(NROWS + 3) / 4, 256, 0, stream>>>(attn, D1);
        bmm_stage1<false><<<NBMM, 256, 0, stream>>>(v, attn, P);
        reduce_kernel<<<(int)(kOutElems / 4 / 256), 256, 0, stream>>>(P, out);
    } else {
        // Fallback without workspace: accumulate via atomics.
        hipMemsetAsync(attn, 0, kAttnElems * sizeof(float), stream);
        hipMemsetAsync(out, 0, kOutElems * sizeof(float), stream);
        dist_kernel<false><<<NDIST, 256, 0, stream>>>(q, k, attn, nullptr);
        softmax_wave<false><<<(NROWS + 3) / 4, 256, 0, stream>>>(attn, attn);
        bmm_stage1<true><<<NBMM, 256, 0, stream>>>(v, attn, out);
    }
}